// Round 1
// baseline (166.002 us; speedup 1.0000x reference)
//
#include <hip/hip_runtime.h>
#include <hip/hip_bf16.h>
#include <math.h>

#define H 24
#define IN 8

// ws layout (floats):
//   [0..191]   Pz[24][8]  = softplus(e_p) * softplus(P)
//   [192..383] Pw[24][8]  = P (raw)
//   [384..407] Az[24]     = softplus(e) * (softplus(W) @ r) + b_z
//   [408..431] Av[24]     = W @ (U*X*r) + b_v
//   [432..455] V0[24]     = v0
#define CST_FLOATS 456

__device__ __forceinline__ float sigm(float x) {
    return 1.0f / (1.0f + __expf(-x));
}
__device__ __forceinline__ float softplus_f(float x) {
    // numerically stable log(1+exp(x))
    return fmaxf(x, 0.0f) + log1pf(__expf(-fabsf(x)));
}

__global__ __launch_bounds__(256) void precompute_kernel(
        const float* __restrict__ W, const float* __restrict__ P,
        const float* __restrict__ b_v, const float* __restrict__ b_z,
        const float* __restrict__ e, const float* __restrict__ e_p,
        const float* __restrict__ c_x, const float* __restrict__ c_u,
        const float* __restrict__ c_U, const float* __restrict__ v0,
        const float* __restrict__ X0, const float* __restrict__ U0,
        float* __restrict__ cst) {
    __shared__ float rr[H];   // r = sigmoid(v0)
    __shared__ float mm[H];   // U * X * r
    const int t = threadIdx.x;
    const float spe  = softplus_f(e[0]);
    const float spep = softplus_f(e_p[0]);

    if (t < H) {
        const float r = sigm(v0[t]);
        rr[t] = r;
        // z_min=0.001, z_max=0.1, delta_t=1.0
        const float zx   = 0.001f + 0.099f * sigm(c_x[t]);
        const float X    = zx + (1.0f - zx) * X0[t] - U0[t] * X0[t] * r;
        const float zu   = 0.001f + 0.099f * sigm(c_u[t]);
        const float Ucap = 0.9f * sigm(c_U[t]);
        float U = Ucap * zu + (1.0f - zu) * U0[t] + Ucap * (1.0f - U0[t]) * r;
        U = fminf(fmaxf(U, Ucap), 1.0f);   // clip to [Ucap, 1]
        mm[t] = U * X * r;
    }
    __syncthreads();
    if (t < H) {
        float kr = 0.0f, wc = 0.0f;
        #pragma unroll
        for (int j = 0; j < H; ++j) {
            const float w = W[t * H + j];
            kr = fmaf(softplus_f(w), rr[j], kr);
            wc = fmaf(w, mm[j], wc);
        }
        cst[384 + t] = fmaf(spe, kr, b_z[t]);
        cst[408 + t] = wc + b_v[t];
        cst[432 + t] = v0[t];
    }
    for (int k = t; k < H * IN; k += blockDim.x) {
        cst[k]       = spep * softplus_f(P[k]);
        cst[192 + k] = P[k];
    }
}

// Each block: 256 batch columns. Thread = one column; writes transposed via LDS.
__global__ __launch_bounds__(256) void cbrnn_main_kernel(
        const float* __restrict__ x,    // (IN, B) row-major
        const float* __restrict__ cst,  // CST_FLOATS
        float* __restrict__ out,        // (B, H) row-major
        int B) {
    __shared__ float sC[CST_FLOATS];
    __shared__ float vs[H][257];       // padded: bank(h,c) = (h+c)&31

    const int tid = threadIdx.x;
    const long b0 = (long)blockIdx.x * 256;
    const long b  = b0 + tid;

    for (int k = tid; k < CST_FLOATS; k += 256) sC[k] = cst[k];

    float xv[IN];
    const bool valid = (b < (long)B);
    if (valid) {
        #pragma unroll
        for (int i = 0; i < IN; ++i) xv[i] = x[(long)i * B + b];
    }
    __syncthreads();

    const float* Pz = sC;
    const float* Pw = sC + 192;
    const float* Az = sC + 384;
    const float* Av = sC + 408;
    const float* V0 = sC + 432;

    if (valid) {
        #pragma unroll
        for (int h = 0; h < H; ++h) {
            float sz = Az[h];
            float sv = Av[h];
            #pragma unroll
            for (int i = 0; i < IN; ++i) {
                sz = fmaf(Pz[h * IN + i], xv[i], sz);
                sv = fmaf(Pw[h * IN + i], xv[i], sv);
            }
            const float zt = 0.1f * sigm(sz);          // dt * sigmoid(...)
            const float v  = (1.0f - zt) * V0[h] + 0.1f * sv;
            vs[h][tid] = v;
        }
    }
    __syncthreads();

    // Coalesced float4 stores of this block's contiguous out region.
    const int ncols = (int)min((long)256, (long)B - b0);
    if (ncols <= 0) return;
    const int nvec = ncols * (H / 4);                  // float4 count (H=24 -> 6/col)
    float4* out4 = (float4*)(out + b0 * H);
    #pragma unroll
    for (int it = 0; it < 6; ++it) {
        const int k4 = it * 256 + tid;
        if (k4 < nvec) {
            const unsigned pos = 4u * (unsigned)k4;
            const unsigned c   = pos / 24u;            // column within block
            const unsigned h0  = pos - c * 24u;        // 0,4,8,12,16,20 (never crosses row)
            float4 o;
            o.x = vs[h0 + 0][c];
            o.y = vs[h0 + 1][c];
            o.z = vs[h0 + 2][c];
            o.w = vs[h0 + 3][c];
            out4[k4] = o;
        }
    }
}

extern "C" void kernel_launch(void* const* d_in, const int* in_sizes, int n_in,
                              void* d_out, int out_size, void* d_ws, size_t ws_size,
                              hipStream_t stream) {
    const float* x   = (const float*)d_in[0];
    const float* W   = (const float*)d_in[1];
    const float* P   = (const float*)d_in[2];
    const float* b_v = (const float*)d_in[3];
    const float* b_z = (const float*)d_in[4];
    const float* e   = (const float*)d_in[5];
    const float* e_p = (const float*)d_in[6];
    const float* c_x = (const float*)d_in[7];
    const float* c_u = (const float*)d_in[8];
    const float* c_U = (const float*)d_in[9];
    const float* v0  = (const float*)d_in[10];
    const float* X0  = (const float*)d_in[11];
    const float* U0  = (const float*)d_in[12];
    float* out = (float*)d_out;
    float* cst = (float*)d_ws;

    const int B = in_sizes[0] / IN;

    precompute_kernel<<<1, 256, 0, stream>>>(W, P, b_v, b_z, e, e_p,
                                             c_x, c_u, c_U, v0, X0, U0, cst);
    const int grid = (B + 255) / 256;
    cbrnn_main_kernel<<<grid, 256, 0, stream>>>(x, cst, out, B);
}